// Round 5
// baseline (2559.080 us; speedup 1.0000x reference)
//
#include <hip/hip_runtime.h>
#include <hip/hip_bf16.h>
#include <hip/hip_cooperative_groups.h>

namespace cg = cooperative_groups;

#define N_NODES 50000
#define N_EDGES 1600000
#define F_IN    128
#define F_OUT   8
#define K_TAPS  4
#define MAX_POWER 25     // F_OUT*(K_TAPS-1)+1

#define BROWS   64       // rows per bucket
#define NB      782      // ceil(N_NODES / BROWS)
#define CHUNK   4096     // edges per partition block
#define NPART   391      // ceil(N_EDGES / CHUNK)
#define ECAP    2816     // LDS edge-cache capacity per bucket (mean 2048, sigma ~45)

__device__ inline int wave_incl_scan(int v, int lane) {
    #pragma unroll
    for (int off = 1; off < 64; off <<= 1) {
        int t = __shfl_up(v, off, 64);
        if (lane >= off) v += t;
    }
    return v;
}

// ---------------------------------------------------------------------------
// Bucket histogram: per-block LDS hist, one global atomic per (block,bucket)
// ---------------------------------------------------------------------------
__global__ void ghist_kernel(const int4* __restrict__ rows4,
                             int* __restrict__ ghist, int n_quads) {
    __shared__ int lh[NB];
    int tid = threadIdx.x;
    for (int b = tid; b < NB; b += 256) lh[b] = 0;
    __syncthreads();
    int qbeg = blockIdx.x * (CHUNK / 4);
    int qend = min(qbeg + CHUNK / 4, n_quads);
    for (int q = qbeg + tid; q < qend; q += 256) {
        int4 r = rows4[q];
        atomicAdd(&lh[r.x >> 6], 1);
        atomicAdd(&lh[r.y >> 6], 1);
        atomicAdd(&lh[r.z >> 6], 1);
        atomicAdd(&lh[r.w >> 6], 1);
    }
    __syncthreads();
    for (int b = tid; b < NB; b += 256) {
        int c = lh[b];
        if (c) atomicAdd(&ghist[b], c);
    }
}

// ---------------------------------------------------------------------------
// Exclusive scan of 782 bucket counts (single block)
// ---------------------------------------------------------------------------
__global__ void bucket_scan_kernel(const int* __restrict__ ghist,
                                   int* __restrict__ bucket_start,
                                   int* __restrict__ bucket_cursor) {
    __shared__ int wsum[4];
    int tid = threadIdx.x, lane = tid & 63, wid = tid >> 6;
    int b0 = tid * 4;
    int h[4]; int tsum = 0;
    #pragma unroll
    for (int j = 0; j < 4; ++j) {
        h[j] = (b0 + j < NB) ? ghist[b0 + j] : 0;
        tsum += h[j];
    }
    int incl = wave_incl_scan(tsum, lane);
    if (lane == 63) wsum[wid] = incl;
    __syncthreads();
    int woff = 0;
    for (int w = 0; w < wid; ++w) woff += wsum[w];
    int excl = woff + incl - tsum;
    #pragma unroll
    for (int j = 0; j < 4; ++j) {
        if (b0 + j < NB) { bucket_start[b0 + j] = excl; bucket_cursor[b0 + j] = excl; }
        excl += h[j];
    }
    if (tid == 255) bucket_start[NB] = woff + incl;   // == N_EDGES
}

// ---------------------------------------------------------------------------
// Partition edges into buckets with LDS staging (coalesced run writes).
// Payload: int2( (local_row<<16) | col , bits(val) )
// ---------------------------------------------------------------------------
__global__ void partition_kernel(const int* __restrict__ rows,
                                 const int* __restrict__ cols,
                                 const float* __restrict__ vals,
                                 int* __restrict__ bucket_cursor,
                                 int2* __restrict__ edges, int n_edges) {
    __shared__ int lhist[NB];
    __shared__ int lcur[NB];
    __shared__ int lbase[NB];
    __shared__ int2 stage[CHUNK];
    __shared__ unsigned short sbkt[CHUNK];
    __shared__ int wsum[4];
    int tid = threadIdx.x;
    int base = blockIdx.x * CHUNK;
    int cend = min(base + CHUNK, n_edges);

    for (int b = tid; b < NB; b += 256) lhist[b] = 0;
    __syncthreads();
    for (int i = base + tid; i < cend; i += 256)
        atomicAdd(&lhist[rows[i] >> 6], 1);
    __syncthreads();

    // exclusive scan of lhist -> lcur
    int lane = tid & 63, wid = tid >> 6;
    int b0 = tid * 4;
    int h[4]; int tsum = 0;
    #pragma unroll
    for (int j = 0; j < 4; ++j) {
        h[j] = (b0 + j < NB) ? lhist[b0 + j] : 0;
        tsum += h[j];
    }
    int incl = wave_incl_scan(tsum, lane);
    if (lane == 63) wsum[wid] = incl;
    __syncthreads();
    int woff = 0;
    for (int w = 0; w < wid; ++w) woff += wsum[w];
    int excl = woff + incl - tsum;
    #pragma unroll
    for (int j = 0; j < 4; ++j) {
        if (b0 + j < NB) lcur[b0 + j] = excl;
        excl += h[j];
    }
    __syncthreads();

    // reserve global space per non-empty bucket
    for (int b = tid; b < NB; b += 256) {
        int c = lhist[b];
        if (c) {
            int g = atomicAdd(&bucket_cursor[b], c);
            lbase[b] = g - lcur[b];
        }
    }
    __syncthreads();

    // stage edges sorted-by-bucket in LDS
    for (int i = base + tid; i < cend; i += 256) {
        int r = rows[i], c = cols[i];
        float v = vals[i];
        int b = r >> 6;
        int pos = atomicAdd(&lcur[b], 1);
        stage[pos] = make_int2(((r & 63) << 16) | c, __float_as_int(v));
        sbkt[pos] = (unsigned short)b;
    }
    __syncthreads();

    // write out: consecutive staged slots -> consecutive global slots per run
    int cn = cend - base;
    for (int i = tid; i < cn; i += 256) {
        int b = sbkt[i];
        edges[lbase[b] + i] = stage[i];
    }
}

// ---------------------------------------------------------------------------
// Persistent cooperative chain: rowsum + 25 SpMV iterations + combine.
// One block per bucket; edges cached in LDS; y accumulated in LDS.
// ---------------------------------------------------------------------------
__global__ __launch_bounds__(256, 4)
void chain_kernel(const int* __restrict__ bucket_start,
                  const int2* __restrict__ edges,
                  const float* __restrict__ x,
                  const float* __restrict__ coeff,
                  float* __restrict__ u,
                  float* __restrict__ buf0,
                  float* __restrict__ buf1,
                  float* __restrict__ y, int n_nodes) {
    __shared__ int2  ecache[ECAP];
    __shared__ float acc[BROWS];
    __shared__ float yacc[BROWS * F_OUT];
    __shared__ float lcoeff[F_OUT * K_TAPS];

    cg::grid_group grid = cg::this_grid();
    int tid = threadIdx.x;
    int b = blockIdx.x;

    // --- init LDS state ---
    if (tid < BROWS) acc[tid] = 0.f;
    for (int j = tid; j < BROWS * F_OUT; j += 256) yacc[j] = 0.f;
    if (tid < F_OUT * K_TAPS) lcoeff[tid] = coeff[tid];

    // --- load this bucket's edge slice into LDS ---
    int beg = bucket_start[b];
    int cnt = bucket_start[b + 1] - beg;
    int cached = min(cnt, ECAP);
    for (int i = tid; i < cached; i += 256) ecache[i] = edges[beg + i];

    // --- rowsum phase: u[n] = sum_f x[n,f]  (grid-stride, one wave per node) ---
    {
        int lane = tid & 63;
        int wave = (b * 256 + tid) >> 6;
        int n_waves = NB * 4;
        for (int node = wave; node < n_nodes; node += n_waves) {
            const float2* xp = (const float2*)(x + (size_t)node * F_IN);
            float2 v = xp[lane];
            float s = v.x + v.y;
            #pragma unroll
            for (int off = 32; off > 0; off >>= 1)
                s += __shfl_down(s, off, 64);
            if (lane == 0) u[node] = s;
        }
    }
    grid.sync();   // u + LDS init visible

    // --- 25 chained SpMVs ---
    for (int p = 0; p < MAX_POWER; ++p) {
        const float* src = (p == 0) ? u : ((p & 1) ? buf0 : buf1);
        float* dst = (p & 1) ? buf1 : buf0;

        for (int i = tid; i < cached; i += 256) {
            int2 ev = ecache[i];
            atomicAdd(&acc[ev.x >> 16], __int_as_float(ev.y) * src[ev.x & 0xFFFF]);
        }
        for (int i = cached + tid; i < cnt; i += 256) {   // overflow fallback (rare)
            int2 ev = edges[beg + i];
            atomicAdd(&acc[ev.x >> 16], __int_as_float(ev.y) * src[ev.x & 0xFFFF]);
        }
        __syncthreads();

        if (tid < BROWS) {
            int row = b * BROWS + tid;
            float val = acc[tid];
            if (row < n_nodes) dst[row] = val;
            acc[tid] = 0.f;
            // fold into y: power p feeds output o at tap k = p - 3o (0..3)
            #pragma unroll
            for (int o = 0; o < F_OUT; ++o) {
                int k = p - (K_TAPS - 1) * o;
                if (k >= 0 && k < K_TAPS)
                    yacc[tid * F_OUT + o] += lcoeff[o * K_TAPS + k] * val;
            }
        }
        if (p < MAX_POWER - 1)
            grid.sync();   // dst visible to all blocks; acc reset done
    }

    // --- write y rows owned by this bucket ---
    __syncthreads();
    for (int j = tid; j < BROWS * F_OUT; j += 256) {
        int row = b * BROWS + (j >> 3);
        if (row < n_nodes) y[(size_t)row * F_OUT + (j & 7)] = yacc[j];
    }
}

extern "C" void kernel_launch(void* const* d_in, const int* in_sizes, int n_in,
                              void* d_out, int out_size, void* d_ws, size_t ws_size,
                              hipStream_t stream) {
    const float* x        = (const float*)d_in[0];
    const int*   gso_rows = (const int*)d_in[1];
    const int*   gso_cols = (const int*)d_in[2];
    const float* gso_vals = (const float*)d_in[3];
    const float* coeff    = (const float*)d_in[4];
    float* y = (float*)d_out;

    // ws layout: u[N] | buf0[N] | buf1[N] | edges[E] int2 | ghist[NB]
    //            | bucket_start[NB+1] | bucket_cursor[NB]
    float* u     = (float*)d_ws;
    float* buf0  = u + N_NODES;
    float* buf1  = buf0 + N_NODES;
    int2*  edges = (int2*)(buf1 + N_NODES);          // 150000*4 B offset, 8B-aligned
    int*   ghist = (int*)(edges + N_EDGES);
    int*   bucket_start  = ghist + NB;
    int*   bucket_cursor = bucket_start + (NB + 1);

    const int n_quads = N_EDGES / 4;

    // --- bucket CSR build ---
    hipMemsetAsync(ghist, 0, NB * sizeof(int), stream);
    ghist_kernel<<<NPART, 256, 0, stream>>>((const int4*)gso_rows, ghist, n_quads);
    bucket_scan_kernel<<<1, 256, 0, stream>>>(ghist, bucket_start, bucket_cursor);
    partition_kernel<<<NPART, 256, 0, stream>>>(
        gso_rows, gso_cols, gso_vals, bucket_cursor, edges, N_EDGES);

    // --- fused persistent chain (cooperative: grid.sync between iterations) ---
    int n_nodes = N_NODES;
    void* args[] = { (void*)&bucket_start, (void*)&edges, (void*)&x, (void*)&coeff,
                     (void*)&u, (void*)&buf0, (void*)&buf1, (void*)&y, (void*)&n_nodes };
    hipLaunchCooperativeKernel((void*)chain_kernel, dim3(NB), dim3(256),
                               args, 0, stream);
}